// Round 5
// baseline (1374.477 us; speedup 1.0000x reference)
//
#include <hip/hip_runtime.h>
#include <hip/hip_bf16.h>

typedef _Float16 f16;
typedef _Float16 f16x8 __attribute__((ext_vector_type(8)));
typedef _Float16 f16x4 __attribute__((ext_vector_type(4)));
typedef float    f32x4 __attribute__((ext_vector_type(4)));

#define MFMA(a,b,c) __builtin_amdgcn_mfma_f32_16x16x32_f16((a),(b),(c),0,0,0)

#define BATCH 1024
#define T_HIST 50
#define ENC_IN 96
#define ENC_H 128
#define G4 512
#define CDE_H 64
#define NCH 33
#define MLP_H 128
#define NZ 10000
#define NSTEP 16
#define SROWS (BATCH*T_HIST)

__device__ __forceinline__ float sigf(float x){
  return __builtin_amdgcn_rcpf(1.f + __builtin_amdgcn_exp2f(-1.44269504f*x));
}
__device__ __forceinline__ float tanhc(float x){
  return 1.f - 2.f*__builtin_amdgcn_rcpf(1.f + __builtin_amdgcn_exp2f(2.88539008f*x));
}

// ---------------------------------------------------------------------------
// Pack weights (fp32 -> fp16 B-fragment layout [ntile][kk][lane][8]).
// W2: permuted (col'=q*64+h -> row h*33+q), zero-padded to 144 tiles
// (36 channels), and tile-remapped n -> n + (n>>4) so the per-channel-group
// stride is 17 tiles = 68KB (breaks 64KB L2 set aliasing).
// ---------------------------------------------------------------------------
__global__ __launch_bounds__(256) void pack_weights(
    const float* __restrict__ wih0, const float* __restrict__ whh0,
    const float* __restrict__ wih1, const float* __restrict__ whh1,
    const float* __restrict__ w1,   const float* __restrict__ wmap,
    const float* __restrict__ w2,   const float* __restrict__ wpred,
    f16* fwih0, f16* fwhh0, f16* fwih1, f16* fwhh1,
    f16* fw1, f16* fwmap, f16* fw2, f16* fwpred)
{
  int bi = blockIdx.x;
  const float* src; f16* dst; int KK, K, n; bool perm=false;
  if      (bi < 32)  { src=wih0;  dst=fwih0;  KK=3; K=96;  n=bi; }
  else if (bi < 64)  { src=whh0;  dst=fwhh0;  KK=4; K=128; n=bi-32; }
  else if (bi < 96)  { src=wih1;  dst=fwih1;  KK=4; K=128; n=bi-64; }
  else if (bi < 128) { src=whh1;  dst=fwhh1;  KK=4; K=128; n=bi-96; }
  else if (bi < 136) { src=w1;    dst=fw1;    KK=2; K=64;  n=bi-128; }
  else if (bi < 140) { src=wmap;  dst=fwmap;  KK=4; K=128; n=bi-136; }
  else if (bi < 284) { src=w2;    dst=fw2;    KK=4; K=128; n=bi-140; perm=true; }
  else               { src=wpred; dst=fwpred; KK=2; K=64;  n=bi-284; }
  int kkI = threadIdx.x>>6, lane = threadIdx.x&63;
  if (kkI >= KK) return;
  int nout = perm ? (n + (n>>4)) : n;
  f16* o = dst + (((size_t)nout*KK + kkI)*64 + lane)*8;
  if(perm && n>=132){
    #pragma unroll
    for(int j=0;j<8;j++) o[j] = (f16)0.f;
    return;
  }
  int col = n*16 + (lane&15);
  int row = perm ? ((col&63)*NCH + (col>>6)) : col;
  int k0  = kkI*32 + (lane>>4)*8;
  const float* s = src + (size_t)row*K + k0;
  #pragma unroll
  for(int j=0;j<8;j++) o[j] = (f16)s[j];
}

// ---------------------------------------------------------------------------
// G0 = history @ Wih0^T + bias, stored t-major [t][b][512] fp16
// ---------------------------------------------------------------------------
__global__ __launch_bounds__(256) void gemm_g0(
    const float* __restrict__ X, const f16* __restrict__ Bf,
    const float* __restrict__ bih, const float* __restrict__ bhh,
    f16* __restrict__ G)
{
  int m = blockIdx.x;
  int w = threadIdx.x>>6, lane = threadIdx.x&63;
  int lm = lane&15, quad = lane>>4;
  int arow = m*16 + lm;
  f16x8 af[3];
  #pragma unroll
  for(int kk=0;kk<3;kk++){
    const float* p = X + (size_t)arow*ENC_IN + kk*32 + quad*8;
    f16x8 v;
    #pragma unroll
    for(int j=0;j<8;j++) v[j] = (f16)p[j];
    af[kk]=v;
  }
  const f16x8* bf8 = (const f16x8*)Bf;
  #pragma unroll
  for(int jt=0;jt<8;jt++){
    int n = w*8 + jt;
    f32x4 acc = {0.f,0.f,0.f,0.f};
    #pragma unroll
    for(int kk=0;kk<3;kk++)
      acc = MFMA(af[kk], bf8[(n*3+kk)*64 + lane], acc);
    int col = n*16 + lm;
    float bias = bih[col] + bhh[col];
    #pragma unroll
    for(int r=0;r<4;r++){
      int srow = m*16 + quad*4 + r;
      int b = srow / T_HIST, t = srow - b*T_HIST;
      G[((size_t)t*BATCH + b)*G4 + col] = (f16)(acc[r] + bias);
    }
  }
}

// G1 = seq0 @ Wih1^T + bias
__global__ __launch_bounds__(256) void gemm_g1(
    const f16* __restrict__ X, const f16* __restrict__ Bf,
    const float* __restrict__ bih, const float* __restrict__ bhh,
    f16* __restrict__ G)
{
  int m = blockIdx.x;
  int w = threadIdx.x>>6, lane = threadIdx.x&63;
  int lm = lane&15, quad = lane>>4;
  int arow = m*16 + lm;
  f16x8 af[4];
  #pragma unroll
  for(int kk=0;kk<4;kk++)
    af[kk] = *(const f16x8*)(X + (size_t)arow*ENC_H + kk*32 + quad*8);
  const f16x8* bf8 = (const f16x8*)Bf;
  #pragma unroll
  for(int jt=0;jt<8;jt++){
    int n = w*8 + jt;
    f32x4 acc = {0.f,0.f,0.f,0.f};
    #pragma unroll
    for(int kk=0;kk<4;kk++)
      acc = MFMA(af[kk], bf8[(n*4+kk)*64 + lane], acc);
    int col = n*16 + lm;
    float bias = bih[col]+bhh[col];
    #pragma unroll
    for(int r=0;r<4;r++){
      int srow = m*16 + quad*4 + r;
      G[(size_t)srow*G4 + col] = (f16)(acc[r]+bias);
    }
  }
}

// ---------------------------------------------------------------------------
// Persistent LSTM: 64 blocks x 8 waves x 16 rows, 50 steps.
// ---------------------------------------------------------------------------
__global__ __launch_bounds__(512,2) void lstm_kernel(
    const f16* __restrict__ G, const f16* __restrict__ Whhf,
    f16* __restrict__ seqout,
    const f16* __restrict__ Wmapf, const float* __restrict__ bmap,
    float* __restrict__ z0, int layer)
{
  __shared__ __align__(16) f16 hbuf[16][136];
  int w = threadIdx.x>>6, lane = threadIdx.x&63;
  int lm = lane&15, quad = lane>>4;
  int row0 = blockIdx.x*16;

  const f16x8* wf8 = (const f16x8*)Whhf;
  f16x8 Bf[4][4];
  #pragma unroll
  for(int m=0;m<4;m++){
    int n = w + 8*m;
    #pragma unroll
    for(int kk=0;kk<4;kk++)
      Bf[m][kk] = wf8[(n*4+kk)*64 + lane];
  }
  for(int i=threadIdx.x;i<16*136;i+=512) ((f16*)hbuf)[i] = (f16)0.f;
  float cst[4];
  #pragma unroll
  for(int r=0;r<4;r++) cst[r]=0.f;
  __syncthreads();

  for(int t=0;t<T_HIST;t++){
    float gin[4][4];
    const f16* Gt = G + ((size_t)t*BATCH + row0)*G4;
    #pragma unroll
    for(int m=0;m<4;m++){
      int col = (w+8*m)*16 + lm;
      #pragma unroll
      for(int r=0;r<4;r++)
        gin[m][r] = (float)Gt[(quad*4+r)*G4 + col];
    }
    f16x8 af[4];
    #pragma unroll
    for(int kk=0;kk<4;kk++)
      af[kk] = *(const f16x8*)&hbuf[lm][kk*32 + quad*8];
    f32x4 acc[4];
    #pragma unroll
    for(int m=0;m<4;m++){ acc[m][0]=0.f;acc[m][1]=0.f;acc[m][2]=0.f;acc[m][3]=0.f; }
    #pragma unroll
    for(int m=0;m<4;m++){
      #pragma unroll
      for(int kk=0;kk<4;kk++)
        acc[m] = MFMA(af[kk], Bf[m][kk], acc[m]);
    }
    __syncthreads();
    int hcol = w*16 + lm;
    #pragma unroll
    for(int r=0;r<4;r++){
      float gi = acc[0][r]+gin[0][r], gf = acc[1][r]+gin[1][r];
      float gg = acc[2][r]+gin[2][r], go = acc[3][r]+gin[3][r];
      float c = sigf(gf)*cst[r] + sigf(gi)*tanhc(gg);
      float h = sigf(go)*tanhc(c);
      cst[r]=c;
      hbuf[quad*4+r][hcol] = (f16)h;
      if(layer==0)
        seqout[((size_t)t*BATCH + row0 + quad*4 + r)*ENC_H + hcol] = (f16)h;
    }
    __syncthreads();
  }
  if(layer==1 && w<4){
    f16x8 af[4];
    #pragma unroll
    for(int kk=0;kk<4;kk++)
      af[kk] = *(const f16x8*)&hbuf[lm][kk*32+quad*8];
    const f16x8* mf8 = (const f16x8*)Wmapf;
    float bm = bmap[w*16+lm];
    f32x4 acc = {bm,bm,bm,bm};
    #pragma unroll
    for(int kk=0;kk<4;kk++)
      acc = MFMA(af[kk], mf8[(w*4+kk)*64+lane], acc);
    #pragma unroll
    for(int r=0;r<4;r++)
      z0[(size_t)(row0+quad*4+r)*CDE_H + w*16+lm] = tanhc(acc[r]);
  }
}

// ---------------------------------------------------------------------------
// Persistent CDE: 64 blocks x 1024 threads x 16 rows. RK state in registers.
// Stage loop fully unrolled (compile-time RK coefficients). Phase C uses
// stage-invariant constant-offset addressing into the 17-tile-strided W2
// and explicit next-group prefetch (full unroll -> SSA, no reg copies).
// ---------------------------------------------------------------------------
__global__ __launch_bounds__(1024,4) void cde_kernel(
    const float* __restrict__ z0, const float* __restrict__ coeffs,
    const float* __restrict__ times,
    const f16* __restrict__ W1f, const f16* __restrict__ W2f,
    const float* __restrict__ b1, const float* __restrict__ b2,
    const float* __restrict__ gamma_, const float* __restrict__ beta_,
    float* __restrict__ zf)
{
  __shared__ __align__(16) float kpart[4][16][68];
  __shared__ __align__(16) f16   znbuf[16][72];
  __shared__ __align__(16) f16   abuf[16][136];
  __shared__ __align__(16) float dxbuf2[36*16];     // [ch][row]
  __shared__ __align__(16) float cxlds[4*528*3];    // [seg][row][ch][3]
  __shared__ __align__(16) f16x8 w1lds[8*2*64];

  int tid = threadIdx.x;
  int w = tid>>6, lane = tid&63, lm = lane&15, quad = lane>>4;
  int row0 = blockIdx.x*16;
  int arow = w;                     // phase-A ownership: wave = row, lane = col

  for(int i=tid;i<8*2*64;i+=1024) w1lds[i] = ((const f16x8*)W1f)[i];
  for(int t=tid;t<2112;t+=1024){
    int seg = t/528, rem = t-seg*528, r = rem/33, q = rem-r*33;
    const float* cc = coeffs + (((size_t)(row0+r)*4 + seg)*4)*NCH + q;
    cxlds[t*3+0] = cc[NCH];
    cxlds[t*3+1] = cc[2*NCH];
    cxlds[t*3+2] = cc[3*NCH];
  }
  if(tid<48) dxbuf2[(33+tid/16)*16 + (tid&15)] = 0.f;

  float zreg = z0[(size_t)(row0+arow)*CDE_H + lane];
  float k1=0.f,k2=0.f,k3=0.f,k4=0.f,k5=0.f;
  float gam = gamma_[lane], bet = beta_[lane];

  float t0 = times[0], t1 = times[1];
  float dt = (t1-t0)/(float)NSTEP, seg = (t1-t0)*0.25f;
  float invseg = 4.f/(t1-t0);

  // dXdt ownership (waves 8-15)
  int ct = tid - 512;
  int doff=0, doff2=0, ddst=0, ddst2=0;
  if(ct>=0){
    int dr = ct/NCH, dq = ct - dr*NCH;
    doff = (dr*NCH+dq)*3; ddst = dq*16+dr;
    int dq2 = 17+ct;
    doff2 = (15*NCH+dq2)*3; ddst2 = dq2*16+15;
  }
  float b1r = b1[(w&7)*16 + lm];
  int g = w>>2, ws = w&3;
  // phase-C: stage-invariant W2 base (f16x8 units); group i at +i*17*256
  const f16x8* pw = (const f16x8*)W2f + ((size_t)(g*4+ws)*4)*64 + lane;
  float b2r[9];
  #pragma unroll
  for(int i=0;i<9;i++){
    int j = g + 4*i;
    b2r[i] = (j<NCH) ? b2[(ws*16+lm)*NCH + j] : 0.f;
  }
  __syncthreads();

  for(int istep=0;istep<NSTEP;istep++){
    #pragma unroll
    for(int s=0;s<6;s++){
      // ---- phase A: consume prev k, RK combo (compile-time), LN
      {
        float kprev = kpart[0][arow][lane] + kpart[1][arow][lane]
                    + kpart[2][arow][lane] + kpart[3][arow][lane];
        if(s==1) k1=kprev;
        if(s==2) k2=kprev;
        if(s==3) k3=kprev;
        if(s==4) k4=kprev;
        if(s==5) k5=kprev;
        float v = zreg;
        if(s==1) v += dt*0.2f*k1;
        if(s==2) v += dt*((float)(3.0/40.0)*k1 + (float)(9.0/40.0)*k2);
        if(s==3) v += dt*((float)(44.0/45.0)*k1 + (float)(-56.0/15.0)*k2 + (float)(32.0/9.0)*k3);
        if(s==4) v += dt*((float)(19372.0/6561.0)*k1 + (float)(-25360.0/2187.0)*k2
                        + (float)(64448.0/6561.0)*k3 + (float)(-212.0/729.0)*k4);
        if(s==5) v += dt*((float)(9017.0/3168.0)*k1 + (float)(-355.0/33.0)*k2
                        + (float)(46732.0/5247.0)*k3 + (float)(49.0/176.0)*k4
                        + (float)(-5103.0/18656.0)*k5);
        float sum = v, ssq = v*v;
        #pragma unroll
        for(int m=1;m<64;m<<=1){
          sum += __shfl_xor(sum, m);
          ssq += __shfl_xor(ssq, m);
        }
        float mu   = sum*(1.f/CDE_H);
        float var  = ssq*(1.f/CDE_H) - mu*mu;
        float rstd = rsqrtf(var + 1e-5f);
        znbuf[arow][lane] = (f16)(((v-mu)*rstd)*gam + bet);
      }
      __syncthreads();
      // ---- phase B: GEMM1 (waves 0-7) || dXdt (waves 8-15)
      if(w<8){
        f16x8 af1[2];
        #pragma unroll
        for(int kk=0;kk<2;kk++)
          af1[kk] = *(const f16x8*)&znbuf[lm][kk*32+quad*8];
        f32x4 acc={0.f,0.f,0.f,0.f};
        #pragma unroll
        for(int kk=0;kk<2;kk++)
          acc = MFMA(af1[kk], w1lds[(w*2+kk)*64+lane], acc);
        int col = w*16+lm;
        #pragma unroll
        for(int r=0;r<4;r++){
          float a = acc[r]+b1r;
          abuf[quad*4+r][col] = (f16)(a>0.f? a:0.f);
        }
      } else {
        const float cC[6] = {0.f,0.2f,0.3f,0.8f,(float)(8.0/9.0),1.f};
        float ts = t0 + ((float)istep + cC[s])*dt;
        int idxt = (int)floorf((ts-t0)*invseg);
        idxt = min(3, max(0, idxt));
        float u = ts - (t0 + (float)idxt*seg);
        int base = idxt*1584;
        {
          float c1=cxlds[base+doff], c2=cxlds[base+doff+1], c3=cxlds[base+doff+2];
          dxbuf2[ddst] = c1 + u*(2.f*c2 + 3.f*c3*u);
        }
        if(ct<16){
          float c1=cxlds[base+doff2], c2=cxlds[base+doff2+1], c3=cxlds[base+doff2+2];
          dxbuf2[ddst2] = c1 + u*(2.f*c2 + 3.f*c3*u);
        }
      }
      __syncthreads();
      // ---- phase C: GEMM2 + tanh + einsum; explicit prefetch pipeline
      {
        f16x8 af2[4];
        #pragma unroll
        for(int kk=0;kk<4;kk++)
          af2[kk] = *(const f16x8*)&abuf[lm][kk*32+quad*8];
        f32x4 kacc = {0.f,0.f,0.f,0.f};
        f16x8 c0 = pw[0*4352 + 0];
        f16x8 c1 = pw[0*4352 + 64];
        f16x8 c2 = pw[0*4352 + 128];
        f16x8 c3 = pw[0*4352 + 192];
        #pragma unroll
        for(int i=0;i<9;i++){
          f16x8 n0,n1,n2,n3;
          if(i<8){
            n0 = pw[(i+1)*4352 + 0];
            n1 = pw[(i+1)*4352 + 64];
            n2 = pw[(i+1)*4352 + 128];
            n3 = pw[(i+1)*4352 + 192];
          }
          int j = g + 4*i;
          f32x4 dx4 = *(const f32x4*)&dxbuf2[j*16 + quad*4];
          f32x4 a2 = {0.f,0.f,0.f,0.f};
          a2 = MFMA(af2[0],c0,a2);
          a2 = MFMA(af2[1],c1,a2);
          a2 = MFMA(af2[2],c2,a2);
          a2 = MFMA(af2[3],c3,a2);
          float bv = b2r[i];
          #pragma unroll
          for(int r=0;r<4;r++)
            kacc[r] += tanhc(a2[r]+bv)*dx4[r];
          c0=n0; c1=n1; c2=n2; c3=n3;
        }
        #pragma unroll
        for(int r=0;r<4;r++)
          kpart[g][quad*4+r][ws*16+lm] = kacc[r];
      }
      __syncthreads();
    }
    // ---- z update (registers; consumes stage-5 partials)
    {
      float k6 = kpart[0][arow][lane] + kpart[1][arow][lane]
               + kpart[2][arow][lane] + kpart[3][arow][lane];
      zreg += dt*( (float)(35.0/384.0)*k1 + (float)(500.0/1113.0)*k3
                 + (float)(125.0/192.0)*k4 + (float)(-2187.0/6784.0)*k5
                 + (float)(11.0/84.0)*k6 );
      if(istep==NSTEP-1)
        zf[(size_t)(row0+arow)*CDE_H + lane] = zreg;
    }
  }
}

// ---------------------------------------------------------------------------
// out = zf @ Wpred^T + bpred   (1024 x 10000, fp32 out)
// ---------------------------------------------------------------------------
__global__ __launch_bounds__(256) void gemm_out(
    const float* __restrict__ zfin, const f16* __restrict__ Wpf,
    const float* __restrict__ bpred, float* __restrict__ out)
{
  int m = blockIdx.x, g = blockIdx.y;
  int w = threadIdx.x>>6, lane = threadIdx.x&63, lm=lane&15, quad=lane>>4;
  int arow = m*16+lm;
  f16x8 af[2];
  #pragma unroll
  for(int kk=0;kk<2;kk++){
    const float* p = zfin + (size_t)arow*CDE_H + kk*32 + quad*8;
    f16x8 v;
    #pragma unroll
    for(int j=0;j<8;j++) v[j]=(f16)p[j];
    af[kk]=v;
  }
  const f16x8* wp8 = (const f16x8*)Wpf;
  #pragma unroll
  for(int jt=0;jt<4;jt++){
    int n = g*16 + w*4 + jt;
    if(n >= NZ/16) break;
    f32x4 acc={0.f,0.f,0.f,0.f};
    #pragma unroll
    for(int kk=0;kk<2;kk++)
      acc = MFMA(af[kk], wp8[((size_t)n*2+kk)*64+lane], acc);
    int col = n*16+lm;
    float bp = bpred[col];
    #pragma unroll
    for(int r=0;r<4;r++)
      out[(size_t)(m*16+quad*4+r)*NZ + col] = acc[r]+bp;
  }
}

extern "C" void kernel_launch(void* const* d_in, const int* in_sizes, int n_in,
                              void* d_out, int out_size, void* d_ws, size_t ws_size,
                              hipStream_t stream) {
  (void)in_sizes; (void)n_in; (void)out_size; (void)ws_size;
  const float* history = (const float*)d_in[0];
  const float* coeffs  = (const float*)d_in[1];
  const float* times   = (const float*)d_in[2];
  const float* Wih0 = (const float*)d_in[3];
  const float* Whh0 = (const float*)d_in[4];
  const float* bih0 = (const float*)d_in[5];
  const float* bhh0 = (const float*)d_in[6];
  const float* Wih1 = (const float*)d_in[7];
  const float* Whh1 = (const float*)d_in[8];
  const float* bih1 = (const float*)d_in[9];
  const float* bhh1 = (const float*)d_in[10];
  const float* Wmap = (const float*)d_in[11];
  const float* bmap = (const float*)d_in[12];
  const float* gam  = (const float*)d_in[13];
  const float* bet  = (const float*)d_in[14];
  const float* W1   = (const float*)d_in[15];
  const float* b1   = (const float*)d_in[16];
  const float* W2   = (const float*)d_in[17];
  const float* b2   = (const float*)d_in[18];
  const float* Wpred= (const float*)d_in[19];
  const float* bpred= (const float*)d_in[20];
  float* out = (float*)d_out;

  char* ws = (char*)d_ws;
  size_t off=0;
  auto alloc=[&](size_t bytes)->void*{
    void* p = ws+off; off += (bytes+255)&~(size_t)255; return p;
  };
  f16* G      = (f16*)alloc((size_t)SROWS*G4*sizeof(f16));
  f16* seq0   = (f16*)alloc((size_t)SROWS*ENC_H*sizeof(f16));
  f16* fwih0  = (f16*)alloc((size_t)32*3*64*8*sizeof(f16));
  f16* fwhh0  = (f16*)alloc((size_t)32*4*64*8*sizeof(f16));
  f16* fwih1  = (f16*)alloc((size_t)32*4*64*8*sizeof(f16));
  f16* fwhh1  = (f16*)alloc((size_t)32*4*64*8*sizeof(f16));
  f16* fw1    = (f16*)alloc((size_t)8*2*64*8*sizeof(f16));
  f16* fwmap  = (f16*)alloc((size_t)4*4*64*8*sizeof(f16));
  f16* fw2    = (f16*)alloc((size_t)153*4*64*8*sizeof(f16));
  f16* fwpred = (f16*)alloc((size_t)625*2*64*8*sizeof(f16));
  float* z0   = (float*)alloc((size_t)BATCH*CDE_H*sizeof(float));
  float* zfin = (float*)alloc((size_t)BATCH*CDE_H*sizeof(float));

  pack_weights<<<909,256,0,stream>>>(Wih0,Whh0,Wih1,Whh1,W1,Wmap,W2,Wpred,
      fwih0,fwhh0,fwih1,fwhh1,fw1,fwmap,fw2,fwpred);
  gemm_g0<<<SROWS/16,256,0,stream>>>(history,fwih0,bih0,bhh0,G);
  lstm_kernel<<<64,512,0,stream>>>(G,fwhh0,seq0,fwmap,bmap,z0,0);
  gemm_g1<<<SROWS/16,256,0,stream>>>(seq0,fwih1,bih1,bhh1,G);
  lstm_kernel<<<64,512,0,stream>>>(G,fwhh1,nullptr,fwmap,bmap,z0,1);
  cde_kernel<<<64,1024,0,stream>>>(z0,coeffs,times,fw1,fw2,b1,b2,gam,bet,zfin);
  gemm_out<<<dim3(64,40),256,0,stream>>>(zfin,fwpred,bpred,out);
}

// Round 6
// 834.210 us; speedup vs baseline: 1.6476x; 1.6476x over previous
//
#include <hip/hip_runtime.h>
#include <hip/hip_bf16.h>

typedef _Float16 f16;
typedef _Float16 f16x8 __attribute__((ext_vector_type(8)));
typedef _Float16 f16x4 __attribute__((ext_vector_type(4)));
typedef float    f32x4 __attribute__((ext_vector_type(4)));

#define MFMA(a,b,c) __builtin_amdgcn_mfma_f32_16x16x32_f16((a),(b),(c),0,0,0)

#define BATCH 1024
#define T_HIST 50
#define ENC_IN 96
#define ENC_H 128
#define G4 512
#define CDE_H 64
#define NCH 33
#define MLP_H 128
#define NZ 10000
#define NSTEP 16
#define SROWS (BATCH*T_HIST)

__device__ __forceinline__ float sigf(float x){
  return __builtin_amdgcn_rcpf(1.f + __builtin_amdgcn_exp2f(-1.44269504f*x));
}
__device__ __forceinline__ float tanhc(float x){
  return 1.f - 2.f*__builtin_amdgcn_rcpf(1.f + __builtin_amdgcn_exp2f(2.88539008f*x));
}

// ---------------------------------------------------------------------------
// Pack weights (fp32 -> fp16 B-fragment layout [ntile][kk][lane][8]).
// W2: permuted (col'=q*64+h -> row h*33+q), zero-padded to 144 tiles
// (36 channels), tile-remapped n -> n + (n>>4) (17-tile group stride).
// ---------------------------------------------------------------------------
__global__ __launch_bounds__(256) void pack_weights(
    const float* __restrict__ wih0, const float* __restrict__ whh0,
    const float* __restrict__ wih1, const float* __restrict__ whh1,
    const float* __restrict__ w1,   const float* __restrict__ wmap,
    const float* __restrict__ w2,   const float* __restrict__ wpred,
    f16* fwih0, f16* fwhh0, f16* fwih1, f16* fwhh1,
    f16* fw1, f16* fwmap, f16* fw2, f16* fwpred)
{
  int bi = blockIdx.x;
  const float* src; f16* dst; int KK, K, n; bool perm=false;
  if      (bi < 32)  { src=wih0;  dst=fwih0;  KK=3; K=96;  n=bi; }
  else if (bi < 64)  { src=whh0;  dst=fwhh0;  KK=4; K=128; n=bi-32; }
  else if (bi < 96)  { src=wih1;  dst=fwih1;  KK=4; K=128; n=bi-64; }
  else if (bi < 128) { src=whh1;  dst=fwhh1;  KK=4; K=128; n=bi-96; }
  else if (bi < 136) { src=w1;    dst=fw1;    KK=2; K=64;  n=bi-128; }
  else if (bi < 140) { src=wmap;  dst=fwmap;  KK=4; K=128; n=bi-136; }
  else if (bi < 284) { src=w2;    dst=fw2;    KK=4; K=128; n=bi-140; perm=true; }
  else               { src=wpred; dst=fwpred; KK=2; K=64;  n=bi-284; }
  int kkI = threadIdx.x>>6, lane = threadIdx.x&63;
  if (kkI >= KK) return;
  int nout = perm ? (n + (n>>4)) : n;
  f16* o = dst + (((size_t)nout*KK + kkI)*64 + lane)*8;
  if(perm && n>=132){
    #pragma unroll
    for(int j=0;j<8;j++) o[j] = (f16)0.f;
    return;
  }
  int col = n*16 + (lane&15);
  int row = perm ? ((col&63)*NCH + (col>>6)) : col;
  int k0  = kkI*32 + (lane>>4)*8;
  const float* s = src + (size_t)row*K + k0;
  #pragma unroll
  for(int j=0;j<8;j++) o[j] = (f16)s[j];
}

// ---------------------------------------------------------------------------
// G0 = history @ Wih0^T + bias, stored t-major [t][b][512] fp16
// ---------------------------------------------------------------------------
__global__ __launch_bounds__(256) void gemm_g0(
    const float* __restrict__ X, const f16* __restrict__ Bf,
    const float* __restrict__ bih, const float* __restrict__ bhh,
    f16* __restrict__ G)
{
  int m = blockIdx.x;
  int w = threadIdx.x>>6, lane = threadIdx.x&63;
  int lm = lane&15, quad = lane>>4;
  int arow = m*16 + lm;
  f16x8 af[3];
  #pragma unroll
  for(int kk=0;kk<3;kk++){
    const float* p = X + (size_t)arow*ENC_IN + kk*32 + quad*8;
    f16x8 v;
    #pragma unroll
    for(int j=0;j<8;j++) v[j] = (f16)p[j];
    af[kk]=v;
  }
  const f16x8* bf8 = (const f16x8*)Bf;
  #pragma unroll
  for(int jt=0;jt<8;jt++){
    int n = w*8 + jt;
    f32x4 acc = {0.f,0.f,0.f,0.f};
    #pragma unroll
    for(int kk=0;kk<3;kk++)
      acc = MFMA(af[kk], bf8[(n*3+kk)*64 + lane], acc);
    int col = n*16 + lm;
    float bias = bih[col] + bhh[col];
    #pragma unroll
    for(int r=0;r<4;r++){
      int srow = m*16 + quad*4 + r;
      int b = srow / T_HIST, t = srow - b*T_HIST;
      G[((size_t)t*BATCH + b)*G4 + col] = (f16)(acc[r] + bias);
    }
  }
}

// G1 = seq0 @ Wih1^T + bias
__global__ __launch_bounds__(256) void gemm_g1(
    const f16* __restrict__ X, const f16* __restrict__ Bf,
    const float* __restrict__ bih, const float* __restrict__ bhh,
    f16* __restrict__ G)
{
  int m = blockIdx.x;
  int w = threadIdx.x>>6, lane = threadIdx.x&63;
  int lm = lane&15, quad = lane>>4;
  int arow = m*16 + lm;
  f16x8 af[4];
  #pragma unroll
  for(int kk=0;kk<4;kk++)
    af[kk] = *(const f16x8*)(X + (size_t)arow*ENC_H + kk*32 + quad*8);
  const f16x8* bf8 = (const f16x8*)Bf;
  #pragma unroll
  for(int jt=0;jt<8;jt++){
    int n = w*8 + jt;
    f32x4 acc = {0.f,0.f,0.f,0.f};
    #pragma unroll
    for(int kk=0;kk<4;kk++)
      acc = MFMA(af[kk], bf8[(n*4+kk)*64 + lane], acc);
    int col = n*16 + lm;
    float bias = bih[col]+bhh[col];
    #pragma unroll
    for(int r=0;r<4;r++){
      int srow = m*16 + quad*4 + r;
      G[(size_t)srow*G4 + col] = (f16)(acc[r]+bias);
    }
  }
}

// ---------------------------------------------------------------------------
// Persistent LSTM: 64 blocks x 8 waves x 16 rows, 50 steps.
// ---------------------------------------------------------------------------
__global__ __launch_bounds__(512,2) void lstm_kernel(
    const f16* __restrict__ G, const f16* __restrict__ Whhf,
    f16* __restrict__ seqout,
    const f16* __restrict__ Wmapf, const float* __restrict__ bmap,
    float* __restrict__ z0, int layer)
{
  __shared__ __align__(16) f16 hbuf[16][136];
  int w = threadIdx.x>>6, lane = threadIdx.x&63;
  int lm = lane&15, quad = lane>>4;
  int row0 = blockIdx.x*16;

  const f16x8* wf8 = (const f16x8*)Whhf;
  f16x8 Bf[4][4];
  #pragma unroll
  for(int m=0;m<4;m++){
    int n = w + 8*m;
    #pragma unroll
    for(int kk=0;kk<4;kk++)
      Bf[m][kk] = wf8[(n*4+kk)*64 + lane];
  }
  for(int i=threadIdx.x;i<16*136;i+=512) ((f16*)hbuf)[i] = (f16)0.f;
  float cst[4];
  #pragma unroll
  for(int r=0;r<4;r++) cst[r]=0.f;
  __syncthreads();

  for(int t=0;t<T_HIST;t++){
    float gin[4][4];
    const f16* Gt = G + ((size_t)t*BATCH + row0)*G4;
    #pragma unroll
    for(int m=0;m<4;m++){
      int col = (w+8*m)*16 + lm;
      #pragma unroll
      for(int r=0;r<4;r++)
        gin[m][r] = (float)Gt[(quad*4+r)*G4 + col];
    }
    f16x8 af[4];
    #pragma unroll
    for(int kk=0;kk<4;kk++)
      af[kk] = *(const f16x8*)&hbuf[lm][kk*32 + quad*8];
    f32x4 acc[4];
    #pragma unroll
    for(int m=0;m<4;m++){ acc[m][0]=0.f;acc[m][1]=0.f;acc[m][2]=0.f;acc[m][3]=0.f; }
    #pragma unroll
    for(int m=0;m<4;m++){
      #pragma unroll
      for(int kk=0;kk<4;kk++)
        acc[m] = MFMA(af[kk], Bf[m][kk], acc[m]);
    }
    __syncthreads();
    int hcol = w*16 + lm;
    #pragma unroll
    for(int r=0;r<4;r++){
      float gi = acc[0][r]+gin[0][r], gf = acc[1][r]+gin[1][r];
      float gg = acc[2][r]+gin[2][r], go = acc[3][r]+gin[3][r];
      float c = sigf(gf)*cst[r] + sigf(gi)*tanhc(gg);
      float h = sigf(go)*tanhc(c);
      cst[r]=c;
      hbuf[quad*4+r][hcol] = (f16)h;
      if(layer==0)
        seqout[((size_t)t*BATCH + row0 + quad*4 + r)*ENC_H + hcol] = (f16)h;
    }
    __syncthreads();
  }
  if(layer==1 && w<4){
    f16x8 af[4];
    #pragma unroll
    for(int kk=0;kk<4;kk++)
      af[kk] = *(const f16x8*)&hbuf[lm][kk*32+quad*8];
    const f16x8* mf8 = (const f16x8*)Wmapf;
    float bm = bmap[w*16+lm];
    f32x4 acc = {bm,bm,bm,bm};
    #pragma unroll
    for(int kk=0;kk<4;kk++)
      acc = MFMA(af[kk], mf8[(w*4+kk)*64+lane], acc);
    #pragma unroll
    for(int r=0;r<4;r++)
      z0[(size_t)(row0+quad*4+r)*CDE_H + w*16+lm] = tanhc(acc[r]);
  }
}

// ---------------------------------------------------------------------------
// Persistent CDE: 64 blocks x 1024 threads x 16 rows. RK state in registers.
// waves_per_eu(4,4) pins 1 block/CU -> 128-VGPR budget (no spills).
// Phase C: dynamic (unroll-1) channel loop, depth-1 explicit prefetch,
// b2 broadcast from LDS. 3 barriers/stage.
// ---------------------------------------------------------------------------
__global__ __launch_bounds__(1024)
__attribute__((amdgpu_waves_per_eu(4,4)))
void cde_kernel(
    const float* __restrict__ z0, const float* __restrict__ coeffs,
    const float* __restrict__ times,
    const f16* __restrict__ W1f, const f16* __restrict__ W2f,
    const float* __restrict__ b1, const float* __restrict__ b2,
    const float* __restrict__ gamma_, const float* __restrict__ beta_,
    float* __restrict__ zf)
{
  __shared__ __align__(16) float kpart[4][16][68];
  __shared__ __align__(16) f16   znbuf[16][72];
  __shared__ __align__(16) f16   abuf[16][136];
  __shared__ __align__(16) float dxbuf2[36*16];     // [ch][row]
  __shared__ __align__(16) float b2lds[64*36];      // [h][ch] padded
  __shared__ __align__(16) float cxlds[4*528*3];    // [seg][row][ch][3]
  __shared__ __align__(16) f16x8 w1lds[8*2*64];

  int tid = threadIdx.x;
  int w = tid>>6, lane = tid&63, lm = lane&15, quad = lane>>4;
  int row0 = blockIdx.x*16;
  int arow = w;                     // phase-A ownership: wave = row, lane = col

  for(int i=tid;i<8*2*64;i+=1024) w1lds[i] = ((const f16x8*)W1f)[i];
  for(int i=tid;i<64*36;i+=1024){
    int h=i/36, j=i-h*36;
    b2lds[i] = (j<NCH)? b2[h*NCH+j] : 0.f;
  }
  for(int t=tid;t<2112;t+=1024){
    int seg = t/528, rem = t-seg*528, r = rem/33, q = rem-r*33;
    const float* cc = coeffs + (((size_t)(row0+r)*4 + seg)*4)*NCH + q;
    cxlds[t*3+0] = cc[NCH];
    cxlds[t*3+1] = cc[2*NCH];
    cxlds[t*3+2] = cc[3*NCH];
  }
  if(tid<48) dxbuf2[(33+tid/16)*16 + (tid&15)] = 0.f;

  float zreg = z0[(size_t)(row0+arow)*CDE_H + lane];
  float k1=0.f,k2=0.f,k3=0.f,k4=0.f,k5=0.f;
  float gam = gamma_[lane], bet = beta_[lane];

  float t0 = times[0], t1 = times[1];
  float dt = (t1-t0)/(float)NSTEP, seg = (t1-t0)*0.25f;
  float invseg = 4.f/(t1-t0);

  // dXdt ownership (waves 8-15)
  int ct = tid - 512;
  int doff=0, doff2=0, ddst=0, ddst2=0;
  if(ct>=0){
    int dr = ct/NCH, dq = ct - dr*NCH;
    doff = (dr*NCH+dq)*3; ddst = dq*16+dr;
    int dq2 = 17+ct;
    doff2 = (15*NCH+dq2)*3; ddst2 = dq2*16+15;
  }
  float b1r = b1[(w&7)*16 + lm];
  int g = w>>2, ws = w&3;
  // phase-C: W2 base (f16x8 units); group i at +i*17*256 (=4352 units)
  const f16x8* pw = (const f16x8*)W2f + ((size_t)(g*4+ws)*4)*64 + lane;
  int b2base = (ws*16+lm)*36 + g;
  __syncthreads();

  for(int istep=0;istep<NSTEP;istep++){
    #pragma unroll
    for(int s=0;s<6;s++){
      // ---- phase A: consume prev k, RK combo (compile-time), LN
      {
        float kprev = kpart[0][arow][lane] + kpart[1][arow][lane]
                    + kpart[2][arow][lane] + kpart[3][arow][lane];
        if(s==1) k1=kprev;
        if(s==2) k2=kprev;
        if(s==3) k3=kprev;
        if(s==4) k4=kprev;
        if(s==5) k5=kprev;
        float v = zreg;
        if(s==1) v += dt*0.2f*k1;
        if(s==2) v += dt*((float)(3.0/40.0)*k1 + (float)(9.0/40.0)*k2);
        if(s==3) v += dt*((float)(44.0/45.0)*k1 + (float)(-56.0/15.0)*k2 + (float)(32.0/9.0)*k3);
        if(s==4) v += dt*((float)(19372.0/6561.0)*k1 + (float)(-25360.0/2187.0)*k2
                        + (float)(64448.0/6561.0)*k3 + (float)(-212.0/729.0)*k4);
        if(s==5) v += dt*((float)(9017.0/3168.0)*k1 + (float)(-355.0/33.0)*k2
                        + (float)(46732.0/5247.0)*k3 + (float)(49.0/176.0)*k4
                        + (float)(-5103.0/18656.0)*k5);
        float sum = v, ssq = v*v;
        #pragma unroll
        for(int m=1;m<64;m<<=1){
          sum += __shfl_xor(sum, m);
          ssq += __shfl_xor(ssq, m);
        }
        float mu   = sum*(1.f/CDE_H);
        float var  = ssq*(1.f/CDE_H) - mu*mu;
        float rstd = rsqrtf(var + 1e-5f);
        znbuf[arow][lane] = (f16)(((v-mu)*rstd)*gam + bet);
      }
      __syncthreads();
      // ---- phase B: GEMM1 (waves 0-7) || dXdt (waves 8-15)
      if(w<8){
        f16x8 af1[2];
        #pragma unroll
        for(int kk=0;kk<2;kk++)
          af1[kk] = *(const f16x8*)&znbuf[lm][kk*32+quad*8];
        f32x4 acc={0.f,0.f,0.f,0.f};
        #pragma unroll
        for(int kk=0;kk<2;kk++)
          acc = MFMA(af1[kk], w1lds[(w*2+kk)*64+lane], acc);
        int col = w*16+lm;
        #pragma unroll
        for(int r=0;r<4;r++){
          float a = acc[r]+b1r;
          abuf[quad*4+r][col] = (f16)(a>0.f? a:0.f);
        }
      } else {
        const float cC[6] = {0.f,0.2f,0.3f,0.8f,(float)(8.0/9.0),1.f};
        float ts = t0 + ((float)istep + cC[s])*dt;
        int idxt = (int)floorf((ts-t0)*invseg);
        idxt = min(3, max(0, idxt));
        float u = ts - (t0 + (float)idxt*seg);
        int base = idxt*1584;
        {
          float c1=cxlds[base+doff], c2=cxlds[base+doff+1], c3=cxlds[base+doff+2];
          dxbuf2[ddst] = c1 + u*(2.f*c2 + 3.f*c3*u);
        }
        if(ct<16){
          float c1=cxlds[base+doff2], c2=cxlds[base+doff2+1], c3=cxlds[base+doff2+2];
          dxbuf2[ddst2] = c1 + u*(2.f*c2 + 3.f*c3*u);
        }
      }
      __syncthreads();
      // ---- phase C: GEMM2 + tanh + einsum; dynamic loop, depth-1 prefetch
      {
        f16x8 af2[4];
        #pragma unroll
        for(int kk=0;kk<4;kk++)
          af2[kk] = *(const f16x8*)&abuf[lm][kk*32+quad*8];
        f32x4 kacc = {0.f,0.f,0.f,0.f};
        const f16x8* p2 = pw;
        f16x8 c0 = p2[0], c1 = p2[64], c2 = p2[128], c3 = p2[192];
        #pragma unroll 1
        for(int i=0;i<8;i++){
          p2 += 4352;
          f16x8 n0 = p2[0], n1 = p2[64], n2 = p2[128], n3 = p2[192];
          float bv = b2lds[b2base + 4*i];
          f32x4 dx4 = *(const f32x4*)&dxbuf2[(g+4*i)*16 + quad*4];
          f32x4 a2 = {bv,bv,bv,bv};
          a2 = MFMA(af2[0],c0,a2);
          a2 = MFMA(af2[1],c1,a2);
          a2 = MFMA(af2[2],c2,a2);
          a2 = MFMA(af2[3],c3,a2);
          #pragma unroll
          for(int r=0;r<4;r++)
            kacc[r] += tanhc(a2[r])*dx4[r];
          c0=n0; c1=n1; c2=n2; c3=n3;
        }
        { // epilogue group i=8 (channels 32..35, padded)
          float bv = b2lds[b2base + 32];
          f32x4 dx4 = *(const f32x4*)&dxbuf2[(g+32)*16 + quad*4];
          f32x4 a2 = {bv,bv,bv,bv};
          a2 = MFMA(af2[0],c0,a2);
          a2 = MFMA(af2[1],c1,a2);
          a2 = MFMA(af2[2],c2,a2);
          a2 = MFMA(af2[3],c3,a2);
          #pragma unroll
          for(int r=0;r<4;r++)
            kacc[r] += tanhc(a2[r])*dx4[r];
        }
        #pragma unroll
        for(int r=0;r<4;r++)
          kpart[g][quad*4+r][ws*16+lm] = kacc[r];
      }
      __syncthreads();
    }
    // ---- z update (registers; consumes stage-5 partials)
    {
      float k6 = kpart[0][arow][lane] + kpart[1][arow][lane]
               + kpart[2][arow][lane] + kpart[3][arow][lane];
      zreg += dt*( (float)(35.0/384.0)*k1 + (float)(500.0/1113.0)*k3
                 + (float)(125.0/192.0)*k4 + (float)(-2187.0/6784.0)*k5
                 + (float)(11.0/84.0)*k6 );
      if(istep==NSTEP-1)
        zf[(size_t)(row0+arow)*CDE_H + lane] = zreg;
    }
  }
}

// ---------------------------------------------------------------------------
// out = zf @ Wpred^T + bpred   (1024 x 10000, fp32 out)
// ---------------------------------------------------------------------------
__global__ __launch_bounds__(256) void gemm_out(
    const float* __restrict__ zfin, const f16* __restrict__ Wpf,
    const float* __restrict__ bpred, float* __restrict__ out)
{
  int m = blockIdx.x, g = blockIdx.y;
  int w = threadIdx.x>>6, lane = threadIdx.x&63, lm=lane&15, quad=lane>>4;
  int arow = m*16+lm;
  f16x8 af[2];
  #pragma unroll
  for(int kk=0;kk<2;kk++){
    const float* p = zfin + (size_t)arow*CDE_H + kk*32 + quad*8;
    f16x8 v;
    #pragma unroll
    for(int j=0;j<8;j++) v[j]=(f16)p[j];
    af[kk]=v;
  }
  const f16x8* wp8 = (const f16x8*)Wpf;
  #pragma unroll
  for(int jt=0;jt<4;jt++){
    int n = g*16 + w*4 + jt;
    if(n >= NZ/16) break;
    f32x4 acc={0.f,0.f,0.f,0.f};
    #pragma unroll
    for(int kk=0;kk<2;kk++)
      acc = MFMA(af[kk], wp8[((size_t)n*2+kk)*64+lane], acc);
    int col = n*16+lm;
    float bp = bpred[col];
    #pragma unroll
    for(int r=0;r<4;r++)
      out[(size_t)(m*16+quad*4+r)*NZ + col] = acc[r]+bp;
  }
}

extern "C" void kernel_launch(void* const* d_in, const int* in_sizes, int n_in,
                              void* d_out, int out_size, void* d_ws, size_t ws_size,
                              hipStream_t stream) {
  (void)in_sizes; (void)n_in; (void)out_size; (void)ws_size;
  const float* history = (const float*)d_in[0];
  const float* coeffs  = (const float*)d_in[1];
  const float* times   = (const float*)d_in[2];
  const float* Wih0 = (const float*)d_in[3];
  const float* Whh0 = (const float*)d_in[4];
  const float* bih0 = (const float*)d_in[5];
  const float* bhh0 = (const float*)d_in[6];
  const float* Wih1 = (const float*)d_in[7];
  const float* Whh1 = (const float*)d_in[8];
  const float* bih1 = (const float*)d_in[9];
  const float* bhh1 = (const float*)d_in[10];
  const float* Wmap = (const float*)d_in[11];
  const float* bmap = (const float*)d_in[12];
  const float* gam  = (const float*)d_in[13];
  const float* bet  = (const float*)d_in[14];
  const float* W1   = (const float*)d_in[15];
  const float* b1   = (const float*)d_in[16];
  const float* W2   = (const float*)d_in[17];
  const float* b2   = (const float*)d_in[18];
  const float* Wpred= (const float*)d_in[19];
  const float* bpred= (const float*)d_in[20];
  float* out = (float*)d_out;

  char* ws = (char*)d_ws;
  size_t off=0;
  auto alloc=[&](size_t bytes)->void*{
    void* p = ws+off; off += (bytes+255)&~(size_t)255; return p;
  };
  f16* G      = (f16*)alloc((size_t)SROWS*G4*sizeof(f16));
  f16* seq0   = (f16*)alloc((size_t)SROWS*ENC_H*sizeof(f16));
  f16* fwih0  = (f16*)alloc((size_t)32*3*64*8*sizeof(f16));
  f16* fwhh0  = (f16*)alloc((size_t)32*4*64*8*sizeof(f16));
  f16* fwih1  = (f16*)alloc((size_t)32*4*64*8*sizeof(f16));
  f16* fwhh1  = (f16*)alloc((size_t)32*4*64*8*sizeof(f16));
  f16* fw1    = (f16*)alloc((size_t)8*2*64*8*sizeof(f16));
  f16* fwmap  = (f16*)alloc((size_t)4*4*64*8*sizeof(f16));
  f16* fw2    = (f16*)alloc((size_t)153*4*64*8*sizeof(f16));
  f16* fwpred = (f16*)alloc((size_t)625*2*64*8*sizeof(f16));
  float* z0   = (float*)alloc((size_t)BATCH*CDE_H*sizeof(float));
  float* zfin = (float*)alloc((size_t)BATCH*CDE_H*sizeof(float));

  pack_weights<<<909,256,0,stream>>>(Wih0,Whh0,Wih1,Whh1,W1,Wmap,W2,Wpred,
      fwih0,fwhh0,fwih1,fwhh1,fw1,fwmap,fw2,fwpred);
  gemm_g0<<<SROWS/16,256,0,stream>>>(history,fwih0,bih0,bhh0,G);
  lstm_kernel<<<64,512,0,stream>>>(G,fwhh0,seq0,fwmap,bmap,z0,0);
  gemm_g1<<<SROWS/16,256,0,stream>>>(seq0,fwih1,bih1,bhh1,G);
  lstm_kernel<<<64,512,0,stream>>>(G,fwhh1,nullptr,fwmap,bmap,z0,1);
  cde_kernel<<<64,1024,0,stream>>>(z0,coeffs,times,fw1,fw2,b1,b2,gam,bet,zfin);
  gemm_out<<<dim3(64,40),256,0,stream>>>(zfin,fwpred,bpred,out);
}